// Round 1
// baseline (185.201 us; speedup 1.0000x reference)
//
#include <hip/hip_runtime.h>
#include <hip/hip_bf16.h>

// score[e] = W2 . relu( W1a.emb[src[e]] + W1b.emb[dst[e]] + b1 ) + b2
// Decompose: P[n][jj] = dot(emb[n, 0:128], W1 + (jj&127)*256 + (jj>>7)*128), jj in [0,256)
//   hidden[e][j] = P[src[e]][j] + P[dst[e]][128+j] + b1[j]
// This turns the 39.5 GFLOP edge-GEMM into a 3.3 GFLOP node-GEMM + gather/reduce.

#define BM 16          // nodes per block in the precompute GEMM
#define H  128
#define NJJ 256        // output columns of P per node

__global__ __launch_bounds__(256)
void precompute_P(const float* __restrict__ emb,
                  const float* __restrict__ W1,
                  float* __restrict__ P,
                  int n_nodes) {
    __shared__ __align__(16) float lds_emb[BM][H];
    int block0 = blockIdx.x * BM;
    int rows = n_nodes - block0;
    if (rows > BM) rows = BM;

    // cooperative stage: rows*128 floats, float4 granularity (coalesced)
    {
        const float4* s4 = (const float4*)(emb + (size_t)block0 * H);
        float4* d4 = (float4*)(&lds_emb[0][0]);
        int total4 = rows * (H / 4);            // up to 512
        for (int i = threadIdx.x; i < total4; i += 256) d4[i] = s4[i];
    }
    __syncthreads();

    int jj = threadIdx.x;                        // one output column per thread
    const float4* w4 = (const float4*)(W1 + (jj & 127) * 256 + (jj >> 7) * H);

    float acc[BM];
#pragma unroll
    for (int m = 0; m < BM; ++m) acc[m] = 0.f;

#pragma unroll 4
    for (int kk = 0; kk < H / 4; ++kk) {         // 32 chunks of 4 k's
        float4 w = w4[kk];
#pragma unroll
        for (int m = 0; m < BM; ++m) {
            float4 e = *(const float4*)(&lds_emb[m][kk * 4]);  // LDS broadcast
            acc[m] += w.x * e.x + w.y * e.y + w.z * e.z + w.w * e.w;
        }
    }

    for (int m = 0; m < rows; ++m)
        P[(size_t)(block0 + m) * NJJ + jj] = acc[m];           // coalesced
}

__global__ __launch_bounds__(256)
void edge_score(const float* __restrict__ P,
                const float* __restrict__ b1,
                const float* __restrict__ W2,
                const float* __restrict__ b2,
                const int* __restrict__ src,
                const int* __restrict__ dst,
                float* __restrict__ out,
                int n_edges) {
    int lane = threadIdx.x & 63;
    int wave = (blockIdx.x * (blockDim.x >> 6)) + (threadIdx.x >> 6);
    int nwaves = gridDim.x * (blockDim.x >> 6);

    // lane i owns hidden dims 2i, 2i+1
    float2 b1v = ((const float2*)b1)[lane];
    float2 w2v = ((const float2*)W2)[lane];
    float b2v = b2[0];

    for (int e = wave; e < n_edges; e += nwaves) {
        int s = src[e];
        int d = dst[e];
        float2 a = ((const float2*)(P + (size_t)s * NJJ))[lane];        // cols 0..127
        float2 b = ((const float2*)(P + (size_t)d * NJJ + H))[lane];    // cols 128..255
        float hx = a.x + b.x + b1v.x; hx = hx > 0.f ? hx : 0.f;
        float hy = a.y + b.y + b1v.y; hy = hy > 0.f ? hy : 0.f;
        float p = hx * w2v.x + hy * w2v.y;
#pragma unroll
        for (int off = 32; off; off >>= 1) p += __shfl_xor(p, off, 64);
        if (lane == 0) out[e] = p + b2v;
    }
}

// Fallback if workspace can't hold P (correctness-first, slow).
__global__ __launch_bounds__(128)
void naive_edge(const float* __restrict__ emb,
                const float* __restrict__ W1,
                const float* __restrict__ b1,
                const float* __restrict__ W2,
                const float* __restrict__ b2,
                const int* __restrict__ src,
                const int* __restrict__ dst,
                float* __restrict__ out,
                int n_edges) {
    __shared__ float es[H], ed[H];
    __shared__ float red[2];
    int e = blockIdx.x;
    if (e >= n_edges) return;
    int j = threadIdx.x;                 // 128 threads, one hidden dim each
    int s = src[e], d = dst[e];
    es[j] = emb[(size_t)s * H + j];
    ed[j] = emb[(size_t)d * H + j];
    __syncthreads();
    const float* w = W1 + (size_t)j * 256;
    float acc = b1[j];
    for (int k = 0; k < H; ++k) acc += es[k] * w[k] + ed[k] * w[H + k];
    acc = acc > 0.f ? acc : 0.f;
    float p = acc * W2[j];
#pragma unroll
    for (int off = 32; off; off >>= 1) p += __shfl_xor(p, off, 64);
    int lane = j & 63, wid = j >> 6;
    if (lane == 0) red[wid] = p;
    __syncthreads();
    if (j == 0) out[e] = red[0] + red[1] + b2[0];
}

extern "C" void kernel_launch(void* const* d_in, const int* in_sizes, int n_in,
                              void* d_out, int out_size, void* d_ws, size_t ws_size,
                              hipStream_t stream) {
    const float* emb = (const float*)d_in[0];   // [N, 128]
    const float* W1  = (const float*)d_in[1];   // [128, 256]
    const float* b1  = (const float*)d_in[2];   // [128]
    const float* W2  = (const float*)d_in[3];   // [1, 128]
    const float* b2  = (const float*)d_in[4];   // [1]
    const int*   src = (const int*)d_in[5];     // [E]
    const int*   dst = (const int*)d_in[6];     // [E]
    float* out = (float*)d_out;

    int n_nodes = in_sizes[0] / H;
    int n_edges = in_sizes[5];

    size_t needP = (size_t)n_nodes * NJJ * sizeof(float);
    if (ws_size >= needP) {
        float* P = (float*)d_ws;
        int grid1 = (n_nodes + BM - 1) / BM;
        precompute_P<<<grid1, 256, 0, stream>>>(emb, W1, P, n_nodes);
        edge_score<<<4096, 256, 0, stream>>>(P, b1, W2, b2, src, dst, out, n_edges);
    } else {
        naive_edge<<<n_edges, 128, 0, stream>>>(emb, W1, b1, W2, b2, src, dst, out, n_edges);
    }
}

// Round 2
// 161.897 us; speedup vs baseline: 1.1439x; 1.1439x over previous
//
#include <hip/hip_runtime.h>
#include <hip/hip_bf16.h>

// score[e] = W2 . relu( W1a.emb[src] + W1b.emb[dst] + b1 ) + b2
// P[n][jj] = dot(emb[n,:], W1 + (jj&127)*256 + (jj>>7)*128) (+ b1[jj] for jj<128)
// stored as bf16: hidden[e][j] = P[src][j] + P[dst][128+j]; score = relu(h).W2 + b2

#define H   128
#define BM  32          // nodes per block in precompute
#define NJJ 256

__global__ __launch_bounds__(256)
void precompute_P(const float* __restrict__ emb,
                  const float* __restrict__ W1,
                  const float* __restrict__ b1,
                  __hip_bfloat16* __restrict__ P,
                  int n_nodes) {
    __shared__ __align__(16) float lds_emb[BM][H];
    int block0 = blockIdx.x * BM;
    int rows = n_nodes - block0;
    if (rows > BM) rows = BM;

    {   // cooperative stage, float4 coalesced
        const float4* s4 = (const float4*)(emb + (size_t)block0 * H);
        float4* d4 = (float4*)(&lds_emb[0][0]);
        int total4 = rows * (H / 4);
        for (int i = threadIdx.x; i < total4; i += 256) d4[i] = s4[i];
    }
    __syncthreads();

    // thread tile: 8 rows x 4 cols {c0, c0+64, c0+128, c0+192}
    int c0 = threadIdx.x & 63;
    int ng = threadIdx.x >> 6;                   // row group: rows ng*8 .. ng*8+7
    const float4* rowA = (const float4*)(W1 + (size_t)c0 * 256);        // cols c0 / c0+128
    const float4* rowC = (const float4*)(W1 + (size_t)(c0 + 64) * 256); // cols c0+64 / c0+192

    float acc0[8], acc1[8], acc2[8], acc3[8];
    float b1a = b1[c0], b1b = b1[c0 + 64];
#pragma unroll
    for (int m = 0; m < 8; ++m) { acc0[m] = b1a; acc1[m] = b1b; acc2[m] = 0.f; acc3[m] = 0.f; }

#pragma unroll 2
    for (int kk = 0; kk < H / 4; ++kk) {
        float4 wA0 = rowA[kk];          // col c0,      k-half 0
        float4 wA1 = rowA[kk + 32];     // col c0+128
        float4 wC0 = rowC[kk];          // col c0+64
        float4 wC1 = rowC[kk + 32];     // col c0+192
#pragma unroll
        for (int m = 0; m < 8; ++m) {
            float4 e = *(const float4*)(&lds_emb[ng * 8 + m][kk * 4]);  // LDS broadcast
            acc0[m] += wA0.x*e.x + wA0.y*e.y + wA0.z*e.z + wA0.w*e.w;
            acc1[m] += wC0.x*e.x + wC0.y*e.y + wC0.z*e.z + wC0.w*e.w;
            acc2[m] += wA1.x*e.x + wA1.y*e.y + wA1.z*e.z + wA1.w*e.w;
            acc3[m] += wC1.x*e.x + wC1.y*e.y + wC1.z*e.z + wC1.w*e.w;
        }
    }

    int mmax = rows - ng * 8;
    if (mmax > 8) mmax = 8;
    for (int m = 0; m < mmax; ++m) {
        size_t base = (size_t)(block0 + ng * 8 + m) * NJJ;
        P[base + c0]        = __float2bfloat16(acc0[m]);
        P[base + c0 + 64]   = __float2bfloat16(acc1[m]);
        P[base + c0 + 128]  = __float2bfloat16(acc2[m]);
        P[base + c0 + 192]  = __float2bfloat16(acc3[m]);
    }
}

#define EPI 4   // edges per wave-iteration

__global__ __launch_bounds__(256)
void edge_score(const __hip_bfloat16* __restrict__ P,
                const float* __restrict__ W2,
                const float* __restrict__ b2,
                const int* __restrict__ src,
                const int* __restrict__ dst,
                float* __restrict__ out,
                int n_edges) {
    int lane = threadIdx.x & 63;
    int wave = blockIdx.x * (blockDim.x >> 6) + (threadIdx.x >> 6);
    int nwaves = gridDim.x * (blockDim.x >> 6);

    float2 w2v = ((const float2*)W2)[lane];   // lane owns hidden dims 2*lane, 2*lane+1
    float b2v = b2[0];

    for (int e0 = wave * EPI; e0 < n_edges; e0 += nwaves * EPI) {
        int s[EPI], d[EPI];
#pragma unroll
        for (int i = 0; i < EPI; ++i) {
            int e = e0 + i; if (e > n_edges - 1) e = n_edges - 1;
            s[i] = src[e]; d[i] = dst[e];
        }
        unsigned int av[EPI], bv[EPI];
#pragma unroll
        for (int i = 0; i < EPI; ++i) {       // 8 independent 256B-row gathers in flight
            av[i] = ((const unsigned int*)(P + (size_t)s[i] * NJJ))[lane];
            bv[i] = ((const unsigned int*)(P + (size_t)d[i] * NJJ + H))[lane];
        }
        float p[EPI];
#pragma unroll
        for (int i = 0; i < EPI; ++i) {
            float ax = __uint_as_float(av[i] << 16);
            float ay = __uint_as_float(av[i] & 0xFFFF0000u);
            float bx = __uint_as_float(bv[i] << 16);
            float by = __uint_as_float(bv[i] & 0xFFFF0000u);
            float hx = ax + bx; hx = hx > 0.f ? hx : 0.f;
            float hy = ay + by; hy = hy > 0.f ? hy : 0.f;
            p[i] = hx * w2v.x + hy * w2v.y;
        }
#pragma unroll
        for (int off = 32; off; off >>= 1) {  // 4 interleaved reduce trees (ILP)
#pragma unroll
            for (int i = 0; i < EPI; ++i) p[i] += __shfl_xor(p[i], off, 64);
        }
        if (lane == 0) {
            if (e0 + EPI <= n_edges) {
                float4 o = { p[0] + b2v, p[1] + b2v, p[2] + b2v, p[3] + b2v };
                *(float4*)(out + e0) = o;     // e0 % 4 == 0 -> 16B aligned
            } else {
                for (int i = 0; i < EPI && e0 + i < n_edges; ++i) out[e0 + i] = p[i] + b2v;
            }
        }
    }
}

// Fallback if workspace can't hold P (correctness-first, slow).
__global__ __launch_bounds__(128)
void naive_edge(const float* __restrict__ emb,
                const float* __restrict__ W1,
                const float* __restrict__ b1,
                const float* __restrict__ W2,
                const float* __restrict__ b2,
                const int* __restrict__ src,
                const int* __restrict__ dst,
                float* __restrict__ out,
                int n_edges) {
    __shared__ float es[H], ed[H];
    __shared__ float red[2];
    int e = blockIdx.x;
    if (e >= n_edges) return;
    int j = threadIdx.x;
    int s = src[e], d = dst[e];
    es[j] = emb[(size_t)s * H + j];
    ed[j] = emb[(size_t)d * H + j];
    __syncthreads();
    const float* w = W1 + (size_t)j * 256;
    float acc = b1[j];
    for (int k = 0; k < H; ++k) acc += es[k] * w[k] + ed[k] * w[H + k];
    acc = acc > 0.f ? acc : 0.f;
    float p = acc * W2[j];
#pragma unroll
    for (int off = 32; off; off >>= 1) p += __shfl_xor(p, off, 64);
    int lane = j & 63, wid = j >> 6;
    if (lane == 0) red[wid] = p;
    __syncthreads();
    if (j == 0) out[e] = red[0] + red[1] + b2[0];
}

extern "C" void kernel_launch(void* const* d_in, const int* in_sizes, int n_in,
                              void* d_out, int out_size, void* d_ws, size_t ws_size,
                              hipStream_t stream) {
    const float* emb = (const float*)d_in[0];   // [N, 128]
    const float* W1  = (const float*)d_in[1];   // [128, 256]
    const float* b1  = (const float*)d_in[2];   // [128]
    const float* W2  = (const float*)d_in[3];   // [1, 128]
    const float* b2  = (const float*)d_in[4];   // [1]
    const int*   src = (const int*)d_in[5];     // [E]
    const int*   dst = (const int*)d_in[6];     // [E]
    float* out = (float*)d_out;

    int n_nodes = in_sizes[0] / H;
    int n_edges = in_sizes[5];

    size_t needP = (size_t)n_nodes * NJJ * sizeof(__hip_bfloat16);
    if (ws_size >= needP) {
        __hip_bfloat16* P = (__hip_bfloat16*)d_ws;
        int grid1 = (n_nodes + BM - 1) / BM;
        precompute_P<<<grid1, 256, 0, stream>>>(emb, W1, b1, P, n_nodes);
        edge_score<<<4096, 256, 0, stream>>>(P, W2, b2, src, dst, out, n_edges);
    } else {
        naive_edge<<<n_edges, 128, 0, stream>>>(emb, W1, b1, W2, b2, src, dst, out, n_edges);
    }
}

// Round 3
// 90.368 us; speedup vs baseline: 2.0494x; 1.7915x over previous
//
#include <hip/hip_runtime.h>
#include <hip/hip_bf16.h>

// score[e] = W2 . relu( W1a.emb[src] + W1b.emb[dst] + b1 ) + b2
// P[n][jj] = dot(emb[n,:], W1[(jj&127), (jj>>7)*128 : +128]) (+ b1[jj] for jj<128)
// P stored bf16 (ushort). hidden[e][j] = P[src][j] + P[dst][128+j]; score = relu(h).W2 + b2
// precompute is a [M=50048 x K=128] x [K x N=256] GEMM -> MFMA bf16.

#define H   128
#define NJJ 256
#define BM  64     // nodes per block in MFMA precompute

typedef __attribute__((ext_vector_type(8))) short  frag_ab; // 8 bf16 = 4 VGPR
typedef __attribute__((ext_vector_type(4))) float  f32x4;
typedef __attribute__((ext_vector_type(8))) unsigned short ushort8;

__device__ __forceinline__ unsigned short f2bf(float x) {   // RNE fp32->bf16
    unsigned int u = __float_as_uint(x);
    unsigned int r = u + 0x7FFFu + ((u >> 16) & 1u);
    return (unsigned short)(r >> 16);
}

__global__ __launch_bounds__(256)
void precompute_P_mfma(const float* __restrict__ emb,
                       const float* __restrict__ W1,
                       const float* __restrict__ b1,
                       unsigned short* __restrict__ P,
                       int n_nodes) {
    __shared__ __align__(16) unsigned short ldsA[BM * H];   // 16KB, XOR-swizzled
    int block0 = blockIdx.x * BM;
    int tid  = threadIdx.x;
    int lane = tid & 63;
    int wid  = tid >> 6;
    int wc0  = wid * 64;            // this wave's first output column

    // ---- B fragments: 16 per wave (4 col-frags x 4 k-steps), from global fp32 W1 ----
    // B-operand layout: col = lane&15, k = (lane>>4)*8 + i  (8 contiguous k -> float4 x2)
    frag_ab Bf[4][4];
    {
        int bcol = wc0 + (lane & 15);
        int krun = (lane >> 4) * 8;
        for (int cf = 0; cf < 4; ++cf) {
            int col = bcol + cf * 16;
            const float* wsrc = W1 + (size_t)(col & 127) * 256 + (size_t)(col >> 7) * H;
            for (int ks = 0; ks < 4; ++ks) {
                const float4* p4 = (const float4*)(wsrc + ks * 32 + krun);
                float4 w0 = p4[0], w1 = p4[1];
                frag_ab f;
                f[0] = (short)f2bf(w0.x); f[1] = (short)f2bf(w0.y);
                f[2] = (short)f2bf(w0.z); f[3] = (short)f2bf(w0.w);
                f[4] = (short)f2bf(w1.x); f[5] = (short)f2bf(w1.y);
                f[6] = (short)f2bf(w1.z); f[7] = (short)f2bf(w1.w);
                Bf[cf][ks] = f;
            }
        }
    }

    // ---- stage A tile: 64 rows x 128 k, fp32 -> bf16, swizzled LDS ----
    {
        int row = tid >> 2;                      // 0..63
        int q   = tid & 3;                       // 32-k quarter
        int grow = block0 + row;
        if (grow > n_nodes - 1) grow = n_nodes - 1;   // clamp tail (stores guarded)
        const float4* src = (const float4*)(emb + (size_t)grow * H + q * 32);
        for (int i = 0; i < 4; ++i) {
            float4 a = src[2 * i], b = src[2 * i + 1];
            ushort8 v;
            v[0] = f2bf(a.x); v[1] = f2bf(a.y); v[2] = f2bf(a.z); v[3] = f2bf(a.w);
            v[4] = f2bf(b.x); v[5] = f2bf(b.y); v[6] = f2bf(b.z); v[7] = f2bf(b.w);
            int k0 = q * 32 + i * 8;
            int byte = (row * 256 + k0 * 2) ^ ((row & 7) << 4);
            *(ushort8*)((char*)ldsA + byte) = v;
        }
    }
    __syncthreads();

    // ---- MFMA: each wave computes [64 rows x 64 cols] ----
    f32x4 acc[4][4];
#pragma unroll
    for (int mf = 0; mf < 4; ++mf)
#pragma unroll
        for (int cf = 0; cf < 4; ++cf) acc[mf][cf] = (f32x4){0.f, 0.f, 0.f, 0.f};

#pragma unroll
    for (int ks = 0; ks < 4; ++ks) {
        frag_ab Af[4];
#pragma unroll
        for (int mf = 0; mf < 4; ++mf) {
            int row = mf * 16 + (lane & 15);
            int k   = ks * 32 + (lane >> 4) * 8;
            int byte = (row * 256 + k * 2) ^ ((row & 7) << 4);
            Af[mf] = *(const frag_ab*)((const char*)ldsA + byte);
        }
#pragma unroll
        for (int mf = 0; mf < 4; ++mf)
#pragma unroll
            for (int cf = 0; cf < 4; ++cf)
                acc[mf][cf] = __builtin_amdgcn_mfma_f32_16x16x32_bf16(
                    Af[mf], Bf[cf][ks], acc[mf][cf], 0, 0, 0);
    }

    // ---- epilogue: +b1 (cols<128), cvt bf16, store ----
    // C/D layout: col = lane&15, row = (lane>>4)*4 + reg
    int colbase = wc0 + (lane & 15);
    int rbase   = (lane >> 4) * 4;
    float b1c[4];
#pragma unroll
    for (int cf = 0; cf < 4; ++cf) {
        int col = colbase + cf * 16;
        b1c[cf] = (col < H) ? b1[col] : 0.f;
    }
#pragma unroll
    for (int mf = 0; mf < 4; ++mf) {
#pragma unroll
        for (int cf = 0; cf < 4; ++cf) {
            int col = colbase + cf * 16;
#pragma unroll
            for (int r = 0; r < 4; ++r) {
                int row = block0 + mf * 16 + rbase + r;
                if (row < n_nodes)
                    P[(size_t)row * NJJ + col] = f2bf(acc[mf][cf][r] + b1c[cf]);
            }
        }
    }
}

#define EPI 4   // edges per wave-iteration

__global__ __launch_bounds__(256)
void edge_score(const unsigned short* __restrict__ P,
                const float* __restrict__ W2,
                const float* __restrict__ b2,
                const int* __restrict__ src,
                const int* __restrict__ dst,
                float* __restrict__ out,
                int n_edges) {
    int lane = threadIdx.x & 63;
    int wave = blockIdx.x * (blockDim.x >> 6) + (threadIdx.x >> 6);
    int nwaves = gridDim.x * (blockDim.x >> 6);

    float2 w2v = ((const float2*)W2)[lane];   // lane owns hidden dims 2*lane, 2*lane+1
    float b2v = b2[0];

    for (int e0 = wave * EPI; e0 < n_edges; e0 += nwaves * EPI) {
        int s[EPI], d[EPI];
#pragma unroll
        for (int i = 0; i < EPI; ++i) {
            int e = e0 + i; if (e > n_edges - 1) e = n_edges - 1;
            s[i] = src[e]; d[i] = dst[e];
        }
        unsigned int av[EPI], bv[EPI];
#pragma unroll
        for (int i = 0; i < EPI; ++i) {       // 8 independent row-gathers in flight
            av[i] = ((const unsigned int*)(P + (size_t)s[i] * NJJ))[lane];
            bv[i] = ((const unsigned int*)(P + (size_t)d[i] * NJJ + H))[lane];
        }
        float p[EPI];
#pragma unroll
        for (int i = 0; i < EPI; ++i) {
            float ax = __uint_as_float(av[i] << 16);
            float ay = __uint_as_float(av[i] & 0xFFFF0000u);
            float bx = __uint_as_float(bv[i] << 16);
            float by = __uint_as_float(bv[i] & 0xFFFF0000u);
            float hx = ax + bx; hx = hx > 0.f ? hx : 0.f;
            float hy = ay + by; hy = hy > 0.f ? hy : 0.f;
            p[i] = hx * w2v.x + hy * w2v.y;
        }
#pragma unroll
        for (int off = 32; off; off >>= 1) {  // 4 interleaved reduce trees (ILP)
#pragma unroll
            for (int i = 0; i < EPI; ++i) p[i] += __shfl_xor(p[i], off, 64);
        }
        if (lane == 0) {
            if (e0 + EPI <= n_edges) {
                float4 o = { p[0] + b2v, p[1] + b2v, p[2] + b2v, p[3] + b2v };
                *(float4*)(out + e0) = o;
            } else {
                for (int i = 0; i < EPI && e0 + i < n_edges; ++i) out[e0 + i] = p[i] + b2v;
            }
        }
    }
}

// Fallback if workspace can't hold P (correctness-first, slow).
__global__ __launch_bounds__(128)
void naive_edge(const float* __restrict__ emb,
                const float* __restrict__ W1,
                const float* __restrict__ b1,
                const float* __restrict__ W2,
                const float* __restrict__ b2,
                const int* __restrict__ src,
                const int* __restrict__ dst,
                float* __restrict__ out,
                int n_edges) {
    __shared__ float es[H], ed[H];
    __shared__ float red[2];
    int e = blockIdx.x;
    if (e >= n_edges) return;
    int j = threadIdx.x;
    int s = src[e], d = dst[e];
    es[j] = emb[(size_t)s * H + j];
    ed[j] = emb[(size_t)d * H + j];
    __syncthreads();
    const float* w = W1 + (size_t)j * 256;
    float acc = b1[j];
    for (int k = 0; k < H; ++k) acc += es[k] * w[k] + ed[k] * w[H + k];
    acc = acc > 0.f ? acc : 0.f;
    float p = acc * W2[j];
#pragma unroll
    for (int off = 32; off; off >>= 1) p += __shfl_xor(p, off, 64);
    int lane = j & 63, wid = j >> 6;
    if (lane == 0) red[wid] = p;
    __syncthreads();
    if (j == 0) out[e] = red[0] + red[1] + b2[0];
}

extern "C" void kernel_launch(void* const* d_in, const int* in_sizes, int n_in,
                              void* d_out, int out_size, void* d_ws, size_t ws_size,
                              hipStream_t stream) {
    const float* emb = (const float*)d_in[0];   // [N, 128]
    const float* W1  = (const float*)d_in[1];   // [128, 256]
    const float* b1  = (const float*)d_in[2];   // [128]
    const float* W2  = (const float*)d_in[3];   // [1, 128]
    const float* b2  = (const float*)d_in[4];   // [1]
    const int*   src = (const int*)d_in[5];     // [E]
    const int*   dst = (const int*)d_in[6];     // [E]
    float* out = (float*)d_out;

    int n_nodes = in_sizes[0] / H;
    int n_edges = in_sizes[5];

    size_t needP = (size_t)n_nodes * NJJ * sizeof(unsigned short);
    if (ws_size >= needP) {
        unsigned short* P = (unsigned short*)d_ws;
        int grid1 = (n_nodes + BM - 1) / BM;
        precompute_P_mfma<<<grid1, 256, 0, stream>>>(emb, W1, b1, P, n_nodes);
        edge_score<<<4096, 256, 0, stream>>>(P, W2, b2, src, dst, out, n_edges);
    } else {
        naive_edge<<<n_edges, 128, 0, stream>>>(emb, W1, b1, W2, b2, src, dst, out, n_edges);
    }
}

// Round 4
// 84.480 us; speedup vs baseline: 2.1922x; 1.0697x over previous
//
#include <hip/hip_runtime.h>
#include <hip/hip_bf16.h>

// score[e] = W2 . relu( W1a.emb[src] + W1b.emb[dst] + b1 ) + b2
// P[n][jj] = dot(emb[n,:], W1col jj) (+ b1[jj] for jj<128), stored bf16.
// precompute: [M=n_nodes x K=128] x [K x N=256] MFMA GEMM.
// edge:       A[16 edges][K=128]=relu(Ps+Pd) x B[K][16]=W2 (all cols equal) -> D[edge][*]=score.

#define H   128
#define NJJ 256
#define BM  64
#define EPW 32   // edges per wave-iteration (2 MFMA groups of 16)

typedef __attribute__((ext_vector_type(8))) short  frag_ab;   // 8 bf16
typedef __attribute__((ext_vector_type(4))) float  f32x4;
typedef __attribute__((ext_vector_type(8))) unsigned short ushort8;
typedef __attribute__((ext_vector_type(4))) unsigned int   uint4v;

__device__ __forceinline__ unsigned short f2bf(float x) {   // RNE fp32->bf16
    unsigned int u = __float_as_uint(x);
    unsigned int r = u + 0x7FFFu + ((u >> 16) & 1u);
    return (unsigned short)(r >> 16);
}

// hidden = relu(bf16pairs(s) + bf16pairs(d)) repacked to 8 bf16 (RNE via v_cvt_pk)
__device__ __forceinline__ frag_ab relu_sum(uint4v s, uint4v d) {
    uint4v r;
#pragma unroll
    for (int p = 0; p < 4; ++p) {
        float sl = __uint_as_float(s[p] << 16);
        float sh = __uint_as_float(s[p] & 0xFFFF0000u);
        float dl = __uint_as_float(d[p] << 16);
        float dh = __uint_as_float(d[p] & 0xFFFF0000u);
        float l = sl + dl; l = l > 0.f ? l : 0.f;
        float h = sh + dh; h = h > 0.f ? h : 0.f;
        unsigned int rr;
        asm("v_cvt_pk_bf16_f32 %0, %1, %2" : "=v"(rr) : "v"(l), "v"(h));
        r[p] = rr;
    }
    return __builtin_bit_cast(frag_ab, r);
}

// ---- tiny: W1 -> bf16 [col][k] layout; W2 -> bf16 ----
__global__ __launch_bounds__(256)
void convert_weights(const float* __restrict__ W1, const float* __restrict__ W2,
                     unsigned short* __restrict__ W1c, unsigned short* __restrict__ W2c) {
    int idx = blockIdx.x * 256 + threadIdx.x;          // 32768 total
    int col = idx >> 7, k = idx & 127;
    W1c[idx] = f2bf(W1[(size_t)(col & 127) * 256 + (size_t)(col >> 7) * H + k]);
    if (idx < H) W2c[idx] = f2bf(W2[idx]);
}

__global__ __launch_bounds__(256)
void precompute_P_mfma(const float* __restrict__ emb,
                       const unsigned short* __restrict__ W1c,   // [256][128] bf16
                       const float* __restrict__ b1,
                       unsigned short* __restrict__ P,
                       int n_nodes) {
    __shared__ __align__(16) unsigned short ldsA[BM * H];   // 16KB, XOR-swizzled
    int block0 = blockIdx.x * BM;
    int tid  = threadIdx.x;
    int lane = tid & 63;
    int wid  = tid >> 6;
    int wc0  = wid * 64;            // this wave's first output column

    // B fragments: 16 per wave, each ONE contiguous 16B bf16 load (L2-hot)
    frag_ab Bf[4][4];
    {
        int colb = wc0 + (lane & 15);
        int krun = (lane >> 4) * 8;
#pragma unroll
        for (int cf = 0; cf < 4; ++cf)
#pragma unroll
            for (int ks = 0; ks < 4; ++ks)
                Bf[cf][ks] = *(const frag_ab*)(W1c + (size_t)(colb + cf * 16) * H + ks * 32 + krun);
    }

    // stage A tile: 64 rows x 128 k, fp32 -> bf16, swizzled LDS
    {
        int row = tid >> 2;                      // 0..63
        int q   = tid & 3;                       // 32-k quarter
        int grow = block0 + row;
        if (grow > n_nodes - 1) grow = n_nodes - 1;
        const float4* src = (const float4*)(emb + (size_t)grow * H + q * 32);
        for (int i = 0; i < 4; ++i) {
            float4 a = src[2 * i], b = src[2 * i + 1];
            ushort8 v;
            v[0] = f2bf(a.x); v[1] = f2bf(a.y); v[2] = f2bf(a.z); v[3] = f2bf(a.w);
            v[4] = f2bf(b.x); v[5] = f2bf(b.y); v[6] = f2bf(b.z); v[7] = f2bf(b.w);
            int k0 = q * 32 + i * 8;
            int byte = (row * 256 + k0 * 2) ^ ((row & 7) << 4);
            *(ushort8*)((char*)ldsA + byte) = v;
        }
    }
    __syncthreads();

    // MFMA: each wave computes [64 rows x 64 cols]
    f32x4 acc[4][4];
#pragma unroll
    for (int mf = 0; mf < 4; ++mf)
#pragma unroll
        for (int cf = 0; cf < 4; ++cf) acc[mf][cf] = (f32x4){0.f, 0.f, 0.f, 0.f};

#pragma unroll
    for (int ks = 0; ks < 4; ++ks) {
        frag_ab Af[4];
#pragma unroll
        for (int mf = 0; mf < 4; ++mf) {
            int row = mf * 16 + (lane & 15);
            int k   = ks * 32 + (lane >> 4) * 8;
            int byte = (row * 256 + k * 2) ^ ((row & 7) << 4);
            Af[mf] = *(const frag_ab*)((const char*)ldsA + byte);
        }
#pragma unroll
        for (int mf = 0; mf < 4; ++mf)
#pragma unroll
            for (int cf = 0; cf < 4; ++cf)
                acc[mf][cf] = __builtin_amdgcn_mfma_f32_16x16x32_bf16(
                    Af[mf], Bf[cf][ks], acc[mf][cf], 0, 0, 0);
    }

    // epilogue: +b1 (cols<128), cvt bf16, store. C/D: col=lane&15, row=(lane>>4)*4+r
    int colbase = wc0 + (lane & 15);
    int rbase   = (lane >> 4) * 4;
    float b1c[4];
#pragma unroll
    for (int cf = 0; cf < 4; ++cf) {
        int col = colbase + cf * 16;
        b1c[cf] = (col < H) ? b1[col] : 0.f;
    }
#pragma unroll
    for (int mf = 0; mf < 4; ++mf) {
#pragma unroll
        for (int cf = 0; cf < 4; ++cf) {
            int col = colbase + cf * 16;
#pragma unroll
            for (int r = 0; r < 4; ++r) {
                int row = block0 + mf * 16 + rbase + r;
                if (row < n_nodes)
                    P[(size_t)row * NJJ + col] = f2bf(acc[mf][cf][r] + b1c[cf]);
            }
        }
    }
}

__global__ __launch_bounds__(256)
void edge_score_mfma(const unsigned short* __restrict__ P,
                     const unsigned short* __restrict__ W2c,
                     const float* __restrict__ b2,
                     const int* __restrict__ src,
                     const int* __restrict__ dst,
                     float* __restrict__ out,
                     int n_edges) {
    int lane = threadIdx.x & 63;
    int wave = blockIdx.x * (blockDim.x >> 6) + (threadIdx.x >> 6);
    int nwaves = gridDim.x * (blockDim.x >> 6);

    // B frag: B[k][col] = W2[k] for all 16 cols. lane: col=lane&15, k=(lane>>4)*8+i
    frag_ab Bf[4];
    {
        int krun = (lane >> 4) * 8;
#pragma unroll
        for (int ks = 0; ks < 4; ++ks)
            Bf[ks] = *(const frag_ab*)(W2c + ks * 32 + krun);
    }
    float b2v = b2[0];
    int el = lane & 15;                 // edge index within group (A-row)
    int kb = (lane >> 4) * 16;          // byte offset of this lane's 8-bf16 chunk

    for (int e0 = wave * EPW; e0 < n_edges; e0 += nwaves * EPW) {
        int eA = e0 + el;       if (eA > n_edges - 1) eA = n_edges - 1;
        int eB = e0 + 16 + el;  if (eB > n_edges - 1) eB = n_edges - 1;
        const char* pb = (const char*)P;
        const char* sA = pb + (size_t)src[eA] * 512 + kb;
        const char* dA = pb + (size_t)dst[eA] * 512 + 256 + kb;
        const char* sB = pb + (size_t)src[eB] * 512 + kb;
        const char* dB = pb + (size_t)dst[eB] * 512 + 256 + kb;

        uint4v rsA[4], rdA[4], rsB[4], rdB[4];
#pragma unroll
        for (int ks = 0; ks < 4; ++ks) {        // 16 independent 1KB gathers in flight
            rsA[ks] = *(const uint4v*)(sA + ks * 64);
            rdA[ks] = *(const uint4v*)(dA + ks * 64);
            rsB[ks] = *(const uint4v*)(sB + ks * 64);
            rdB[ks] = *(const uint4v*)(dB + ks * 64);
        }

        f32x4 accA = (f32x4){0.f, 0.f, 0.f, 0.f};
        f32x4 accB = (f32x4){0.f, 0.f, 0.f, 0.f};
#pragma unroll
        for (int ks = 0; ks < 4; ++ks) {
            accA = __builtin_amdgcn_mfma_f32_16x16x32_bf16(relu_sum(rsA[ks], rdA[ks]), Bf[ks], accA, 0, 0, 0);
            accB = __builtin_amdgcn_mfma_f32_16x16x32_bf16(relu_sum(rsB[ks], rdB[ks]), Bf[ks], accB, 0, 0, 0);
        }

        // D: col=lane&15 (all cols equal), row=(lane>>4)*4+r -> edges e0(+16)+4g+r
        if (el == 0) {
            int r0 = (lane >> 4) * 4;
            int ea = e0 + r0, eb = e0 + 16 + r0;
            float4 oA = { accA[0] + b2v, accA[1] + b2v, accA[2] + b2v, accA[3] + b2v };
            float4 oB = { accB[0] + b2v, accB[1] + b2v, accB[2] + b2v, accB[3] + b2v };
            if (eb + 3 < n_edges) {
                *(float4*)(out + ea) = oA;
                *(float4*)(out + eb) = oB;
            } else {
#pragma unroll
                for (int r = 0; r < 4; ++r) {
                    if (ea + r < n_edges) out[ea + r] = accA[r] + b2v;
                    if (eb + r < n_edges) out[eb + r] = accB[r] + b2v;
                }
            }
        }
    }
}

// Fallback if workspace too small (correctness-first, slow).
__global__ __launch_bounds__(128)
void naive_edge(const float* __restrict__ emb,
                const float* __restrict__ W1,
                const float* __restrict__ b1,
                const float* __restrict__ W2,
                const float* __restrict__ b2,
                const int* __restrict__ src,
                const int* __restrict__ dst,
                float* __restrict__ out,
                int n_edges) {
    __shared__ float es[H], ed[H];
    __shared__ float red[2];
    int e = blockIdx.x;
    if (e >= n_edges) return;
    int j = threadIdx.x;
    int s = src[e], d = dst[e];
    es[j] = emb[(size_t)s * H + j];
    ed[j] = emb[(size_t)d * H + j];
    __syncthreads();
    const float* w = W1 + (size_t)j * 256;
    float acc = b1[j];
    for (int k = 0; k < H; ++k) acc += es[k] * w[k] + ed[k] * w[H + k];
    acc = acc > 0.f ? acc : 0.f;
    float p = acc * W2[j];
#pragma unroll
    for (int off = 32; off; off >>= 1) p += __shfl_xor(p, off, 64);
    int lane = j & 63, wid = j >> 6;
    if (lane == 0) red[wid] = p;
    __syncthreads();
    if (j == 0) out[e] = red[0] + red[1] + b2[0];
}

extern "C" void kernel_launch(void* const* d_in, const int* in_sizes, int n_in,
                              void* d_out, int out_size, void* d_ws, size_t ws_size,
                              hipStream_t stream) {
    const float* emb = (const float*)d_in[0];   // [N, 128]
    const float* W1  = (const float*)d_in[1];   // [128, 256]
    const float* b1  = (const float*)d_in[2];   // [128]
    const float* W2  = (const float*)d_in[3];   // [1, 128]
    const float* b2  = (const float*)d_in[4];   // [1]
    const int*   src = (const int*)d_in[5];     // [E]
    const int*   dst = (const int*)d_in[6];     // [E]
    float* out = (float*)d_out;

    int n_nodes = in_sizes[0] / H;
    int n_edges = in_sizes[5];

    size_t needP = (size_t)n_nodes * NJJ * sizeof(unsigned short);
    size_t offW1 = (needP + 255) & ~(size_t)255;
    size_t offW2 = offW1 + (size_t)NJJ * H * sizeof(unsigned short);
    size_t need  = offW2 + 256;

    if (ws_size >= need) {
        unsigned short* P   = (unsigned short*)d_ws;
        unsigned short* W1c = (unsigned short*)((char*)d_ws + offW1);
        unsigned short* W2c = (unsigned short*)((char*)d_ws + offW2);
        convert_weights<<<(NJJ * H) / 256, 256, 0, stream>>>(W1, W2, W1c, W2c);
        int grid1 = (n_nodes + BM - 1) / BM;
        precompute_P_mfma<<<grid1, 256, 0, stream>>>(emb, W1c, b1, P, n_nodes);
        edge_score_mfma<<<1024, 256, 0, stream>>>(P, W2c, b2, src, dst, out, n_edges);
    } else {
        naive_edge<<<n_edges, 128, 0, stream>>>(emb, W1, b1, W2, b2, src, dst, out, n_edges);
    }
}

// Round 5
// 66.032 us; speedup vs baseline: 2.8047x; 1.2794x over previous
//
#include <hip/hip_runtime.h>
#include <hip/hip_bf16.h>

// score[e] = W2 . relu( W1a.emb[src] + W1b.emb[dst] + b1 ) + b2
// P[n][jj] = dot(emb[n,:], W1col jj) (+ b1[jj] for jj<128), stored bf16.
// precompute: [M=n_nodes x K=128] x [K x N=256] MFMA GEMM, LDS-bounce epilogue.
// edge: A[16 edges][K=128]=relu(Ps+Pd) x B[K][16]=W2 (all cols equal), one group of 32/wave.

#define H   128
#define NJJ 256
#define BM  64
#define EPW 32
#define CPAD_SH 264   // ldsC row stride in shorts (528B = 33*16B; breaks 4-row bank cycle)

typedef __attribute__((ext_vector_type(8))) short  frag_ab;   // 8 bf16
typedef __attribute__((ext_vector_type(4))) float  f32x4;
typedef __attribute__((ext_vector_type(8))) unsigned short ushort8;
typedef __attribute__((ext_vector_type(4))) unsigned int   uint4v;

__device__ __forceinline__ unsigned short f2bf(float x) {   // RNE fp32->bf16
    unsigned int u = __float_as_uint(x);
    unsigned int r = u + 0x7FFFu + ((u >> 16) & 1u);
    return (unsigned short)(r >> 16);
}

__device__ __forceinline__ frag_ab relu_sum(uint4v s, uint4v d) {
    uint4v r;
#pragma unroll
    for (int p = 0; p < 4; ++p) {
        float sl = __uint_as_float(s[p] << 16);
        float sh = __uint_as_float(s[p] & 0xFFFF0000u);
        float dl = __uint_as_float(d[p] << 16);
        float dh = __uint_as_float(d[p] & 0xFFFF0000u);
        float l = sl + dl; l = l > 0.f ? l : 0.f;
        float h = sh + dh; h = h > 0.f ? h : 0.f;
        unsigned int rr;
        asm("v_cvt_pk_bf16_f32 %0, %1, %2" : "=v"(rr) : "v"(l), "v"(h));
        r[p] = rr;
    }
    return __builtin_bit_cast(frag_ab, r);
}

// W1 -> bf16 fragment-ready layout W1f; W2 -> bf16 W2c.
// W1f chunk layout: chunk = ((wid*4+cf)*4+ks)*64 + lane ; elem e in [0,8)
//   col = wid*64 + (lane&15) + cf*16 ; k = ks*32 + (lane>>4)*8 + e
__global__ __launch_bounds__(256)
void convert_weights(const float* __restrict__ W1, const float* __restrict__ W2,
                     unsigned short* __restrict__ W1f, unsigned short* __restrict__ W2c) {
    if (blockIdx.x == 128) {
        if (threadIdx.x < H) W2c[threadIdx.x] = f2bf(W2[threadIdx.x]);
        return;
    }
    int idx = blockIdx.x * 256 + threadIdx.x;          // [0, 32768)
    int e     = idx & 7;
    int chunk = idx >> 3;
    int lane  = chunk & 63;
    int ks    = (chunk >> 6) & 3;
    int cf    = (chunk >> 8) & 3;
    int wid   = chunk >> 10;
    int col   = wid * 64 + (lane & 15) + cf * 16;
    int k     = ks * 32 + (lane >> 4) * 8 + e;
    W1f[idx] = f2bf(W1[(size_t)(col & 127) * 256 + (size_t)(col >> 7) * H + k]);
}

__global__ __launch_bounds__(256)
void precompute_P_mfma(const float* __restrict__ emb,
                       const unsigned short* __restrict__ W1f,
                       const float* __restrict__ b1,
                       unsigned short* __restrict__ P,
                       int n_nodes) {
    __shared__ __align__(16) char ldsbuf[BM * CPAD_SH * 2];   // 33792B, A-tile then C-tile (aliased)
    unsigned short* ldsA = (unsigned short*)ldsbuf;           // 16KB swizzled bf16 A
    unsigned short* ldsC = (unsigned short*)ldsbuf;           // 64 x 264 shorts (after barrier)

    int tid  = threadIdx.x;
    int lane = tid & 63;
    int wid  = tid >> 6;
    int block0 = blockIdx.x * BM;
    if (block0 + BM > n_nodes) block0 = n_nodes - BM;   // overlap tail (same values rewritten)
    if (block0 < 0) block0 = 0;

    // B fragments: fully coalesced 1KB/inst from fragment-ready W1f (L2-hot)
    frag_ab Bf[4][4];
#pragma unroll
    for (int cf = 0; cf < 4; ++cf)
#pragma unroll
        for (int ks = 0; ks < 4; ++ks)
            Bf[cf][ks] = *(const frag_ab*)(W1f + ((((size_t)wid * 4 + cf) * 4 + ks) * 64 + lane) * 8);

    // stage A tile: 64 rows x 128 k, fp32 -> bf16, XOR-swizzled LDS
    {
        int row = tid >> 2;
        int q   = tid & 3;
        int grow = block0 + row;
        if (grow > n_nodes - 1) grow = n_nodes - 1;
        const float4* src = (const float4*)(emb + (size_t)grow * H + q * 32);
#pragma unroll
        for (int i = 0; i < 4; ++i) {
            float4 a = src[2 * i], b = src[2 * i + 1];
            ushort8 v;
            v[0] = f2bf(a.x); v[1] = f2bf(a.y); v[2] = f2bf(a.z); v[3] = f2bf(a.w);
            v[4] = f2bf(b.x); v[5] = f2bf(b.y); v[6] = f2bf(b.z); v[7] = f2bf(b.w);
            int k0 = q * 32 + i * 8;
            int byte = (row * 256 + k0 * 2) ^ ((row & 7) << 4);
            *(ushort8*)((char*)ldsA + byte) = v;
        }
    }
    __syncthreads();

    // MFMA: each wave computes [64 rows x 64 cols]
    f32x4 acc[4][4];
#pragma unroll
    for (int mf = 0; mf < 4; ++mf)
#pragma unroll
        for (int cf = 0; cf < 4; ++cf) acc[mf][cf] = (f32x4){0.f, 0.f, 0.f, 0.f};

#pragma unroll
    for (int ks = 0; ks < 4; ++ks) {
        frag_ab Af[4];
#pragma unroll
        for (int mf = 0; mf < 4; ++mf) {
            int row = mf * 16 + (lane & 15);
            int k   = ks * 32 + (lane >> 4) * 8;
            int byte = (row * 256 + k * 2) ^ ((row & 7) << 4);
            Af[mf] = *(const frag_ab*)((const char*)ldsA + byte);
        }
#pragma unroll
        for (int mf = 0; mf < 4; ++mf)
#pragma unroll
            for (int cf = 0; cf < 4; ++cf)
                acc[mf][cf] = __builtin_amdgcn_mfma_f32_16x16x32_bf16(
                    Af[mf], Bf[cf][ks], acc[mf][cf], 0, 0, 0);
    }

    __syncthreads();   // all Af reads done -> safe to overwrite ldsbuf with C-tile

    // epilogue pt1: +b1, cvt, write C-tile to padded LDS
    {
        int colbase = wid * 64 + (lane & 15);
        int rbase   = (lane >> 4) * 4;
        float b1c[4];
#pragma unroll
        for (int cf = 0; cf < 4; ++cf) {
            int col = colbase + cf * 16;
            b1c[cf] = (col < H) ? b1[col] : 0.f;
        }
#pragma unroll
        for (int mf = 0; mf < 4; ++mf)
#pragma unroll
            for (int cf = 0; cf < 4; ++cf) {
                int col = colbase + cf * 16;
#pragma unroll
                for (int r = 0; r < 4; ++r) {
                    int row = mf * 16 + rbase + r;
                    ldsC[row * CPAD_SH + col] = f2bf(acc[mf][cf][r] + b1c[cf]);
                }
            }
    }
    __syncthreads();

    // epilogue pt2: stream C-tile out, fully coalesced 16B/lane (complete 1KB/inst lines)
#pragma unroll
    for (int it = 0; it < 8; ++it) {
        int c   = it * 256 + tid;        // 16B chunk id, [0, 2048)
        int row = c >> 5;
        int off = c & 31;
        ushort8 v = *(const ushort8*)((const char*)ldsC + row * (CPAD_SH * 2) + off * 16);
        *(ushort8*)((char*)P + (size_t)(block0 + row) * 512 + off * 16) = v;
    }
}

__global__ __launch_bounds__(256)
void edge_score_mfma(const unsigned short* __restrict__ P,
                     const unsigned short* __restrict__ W2c,
                     const float* __restrict__ b2,
                     const int* __restrict__ src,
                     const int* __restrict__ dst,
                     float* __restrict__ out,
                     int n_edges) {
    int lane = threadIdx.x & 63;
    int wave = blockIdx.x * 4 + (threadIdx.x >> 6);
    int e0 = wave * EPW;
    if (e0 >= n_edges) return;

    frag_ab Bf[4];
    {
        int krun = (lane >> 4) * 8;
#pragma unroll
        for (int ks = 0; ks < 4; ++ks)
            Bf[ks] = *(const frag_ab*)(W2c + ks * 32 + krun);
    }
    float b2v = b2[0];
    int el = lane & 15;
    int kb = (lane >> 4) * 16;

    int eA = e0 + el;       if (eA > n_edges - 1) eA = n_edges - 1;
    int eB = e0 + 16 + el;  if (eB > n_edges - 1) eB = n_edges - 1;
    const char* pb = (const char*)P;
    const char* sA = pb + (size_t)src[eA] * 512 + kb;
    const char* dA = pb + (size_t)dst[eA] * 512 + 256 + kb;
    const char* sB = pb + (size_t)src[eB] * 512 + kb;
    const char* dB = pb + (size_t)dst[eB] * 512 + 256 + kb;

    uint4v rsA[4], rdA[4], rsB[4], rdB[4];
#pragma unroll
    for (int ks = 0; ks < 4; ++ks) {        // 16 independent gathers in flight
        rsA[ks] = *(const uint4v*)(sA + ks * 64);
        rdA[ks] = *(const uint4v*)(dA + ks * 64);
        rsB[ks] = *(const uint4v*)(sB + ks * 64);
        rdB[ks] = *(const uint4v*)(dB + ks * 64);
    }

    f32x4 accA = (f32x4){0.f, 0.f, 0.f, 0.f};
    f32x4 accB = (f32x4){0.f, 0.f, 0.f, 0.f};
#pragma unroll
    for (int ks = 0; ks < 4; ++ks) {
        accA = __builtin_amdgcn_mfma_f32_16x16x32_bf16(relu_sum(rsA[ks], rdA[ks]), Bf[ks], accA, 0, 0, 0);
        accB = __builtin_amdgcn_mfma_f32_16x16x32_bf16(relu_sum(rsB[ks], rdB[ks]), Bf[ks], accB, 0, 0, 0);
    }

    if (el == 0) {
        int r0 = (lane >> 4) * 4;
        int ea = e0 + r0, eb = e0 + 16 + r0;
        float4 oA = { accA[0] + b2v, accA[1] + b2v, accA[2] + b2v, accA[3] + b2v };
        float4 oB = { accB[0] + b2v, accB[1] + b2v, accB[2] + b2v, accB[3] + b2v };
        if (eb + 3 < n_edges) {
            *(float4*)(out + ea) = oA;
            *(float4*)(out + eb) = oB;
        } else {
#pragma unroll
            for (int r = 0; r < 4; ++r) {
                if (ea + r < n_edges) out[ea + r] = accA[r] + b2v;
                if (eb + r < n_edges) out[eb + r] = accB[r] + b2v;
            }
        }
    }
}

// Fallback if workspace too small (correctness-first, slow).
__global__ __launch_bounds__(128)
void naive_edge(const float* __restrict__ emb,
                const float* __restrict__ W1,
                const float* __restrict__ b1,
                const float* __restrict__ W2,
                const float* __restrict__ b2,
                const int* __restrict__ src,
                const int* __restrict__ dst,
                float* __restrict__ out,
                int n_edges) {
    __shared__ float es[H], ed[H];
    __shared__ float red[2];
    int e = blockIdx.x;
    if (e >= n_edges) return;
    int j = threadIdx.x;
    int s = src[e], d = dst[e];
    es[j] = emb[(size_t)s * H + j];
    ed[j] = emb[(size_t)d * H + j];
    __syncthreads();
    const float* w = W1 + (size_t)j * 256;
    float acc = b1[j];
    for (int k = 0; k < H; ++k) acc += es[k] * w[k] + ed[k] * w[H + k];
    acc = acc > 0.f ? acc : 0.f;
    float p = acc * W2[j];
#pragma unroll
    for (int off = 32; off; off >>= 1) p += __shfl_xor(p, off, 64);
    int lane = j & 63, wid = j >> 6;
    if (lane == 0) red[wid] = p;
    __syncthreads();
    if (j == 0) out[e] = red[0] + red[1] + b2[0];
}

extern "C" void kernel_launch(void* const* d_in, const int* in_sizes, int n_in,
                              void* d_out, int out_size, void* d_ws, size_t ws_size,
                              hipStream_t stream) {
    const float* emb = (const float*)d_in[0];   // [N, 128]
    const float* W1  = (const float*)d_in[1];   // [128, 256]
    const float* b1  = (const float*)d_in[2];   // [128]
    const float* W2  = (const float*)d_in[3];   // [1, 128]
    const float* b2  = (const float*)d_in[4];   // [1]
    const int*   src = (const int*)d_in[5];     // [E]
    const int*   dst = (const int*)d_in[6];     // [E]
    float* out = (float*)d_out;

    int n_nodes = in_sizes[0] / H;
    int n_edges = in_sizes[5];

    size_t needP = (size_t)n_nodes * NJJ * sizeof(unsigned short);
    size_t offW1 = (needP + 255) & ~(size_t)255;
    size_t offW2 = offW1 + (size_t)NJJ * H * sizeof(unsigned short);
    size_t need  = offW2 + 256;

    if (ws_size >= need && n_nodes >= BM) {
        unsigned short* P   = (unsigned short*)d_ws;
        unsigned short* W1f = (unsigned short*)((char*)d_ws + offW1);
        unsigned short* W2c = (unsigned short*)((char*)d_ws + offW2);
        convert_weights<<<129, 256, 0, stream>>>(W1, W2, W1f, W2c);
        int grid1 = (n_nodes + BM - 1) / BM;
        precompute_P_mfma<<<grid1, 256, 0, stream>>>(emb, W1f, b1, P, n_nodes);
        int grid2 = (n_edges + EPW * 4 - 1) / (EPW * 4);
        edge_score_mfma<<<grid2, 256, 0, stream>>>(P, W2c, b2, src, dst, out, n_edges);
    } else {
        naive_edge<<<n_edges, 128, 0, stream>>>(emb, W1, b1, W2, b2, src, dst, out, n_edges);
    }
}

// Round 6
// 64.236 us; speedup vs baseline: 2.8831x; 1.0280x over previous
//
#include <hip/hip_runtime.h>
#include <hip/hip_bf16.h>

// score[e] = W2 . relu( W1a.emb[src] + W1b.emb[dst] + b1 ) + b2
// P[n][jj] = dot(emb[n,:], W1col jj) (+ b1[jj] for jj<128), stored bf16.
// precompute: [M=n_nodes x K=128] x [K x N=256] MFMA GEMM, LDS-bounce epilogue, BM=32.
// edge: A[16 edges][K=128]=relu(Ps+Pd) x B[K][16]=W2 (all cols equal), 32 edges/wave one-shot.
// Edge phase is at the random-gather miss-service roofline (~3.05 TB/s, ~131MB compulsory).

#define H   128
#define NJJ 256
#define BM  32
#define EPW 32
#define CPAD_SH 264   // ldsC row stride in shorts (528B; breaks 4-row bank cycle)

typedef __attribute__((ext_vector_type(8))) short  frag_ab;   // 8 bf16
typedef __attribute__((ext_vector_type(4))) float  f32x4;
typedef __attribute__((ext_vector_type(8))) unsigned short ushort8;
typedef __attribute__((ext_vector_type(4))) unsigned int   uint4v;

__device__ __forceinline__ unsigned short f2bf(float x) {   // RNE fp32->bf16
    unsigned int u = __float_as_uint(x);
    unsigned int r = u + 0x7FFFu + ((u >> 16) & 1u);
    return (unsigned short)(r >> 16);
}

__device__ __forceinline__ frag_ab relu_sum(uint4v s, uint4v d) {
    uint4v r;
#pragma unroll
    for (int p = 0; p < 4; ++p) {
        float sl = __uint_as_float(s[p] << 16);
        float sh = __uint_as_float(s[p] & 0xFFFF0000u);
        float dl = __uint_as_float(d[p] << 16);
        float dh = __uint_as_float(d[p] & 0xFFFF0000u);
        float l = sl + dl; l = l > 0.f ? l : 0.f;
        float h = sh + dh; h = h > 0.f ? h : 0.f;
        unsigned int rr;
        asm("v_cvt_pk_bf16_f32 %0, %1, %2" : "=v"(rr) : "v"(l), "v"(h));
        r[p] = rr;
    }
    return __builtin_bit_cast(frag_ab, r);
}

// W1 -> bf16 fragment-ready layout W1f; W2 -> bf16 W2c.
// W1f chunk layout: chunk = ((wid*4+cf)*4+ks)*64 + lane ; elem e in [0,8)
//   col = wid*64 + (lane&15) + cf*16 ; k = ks*32 + (lane>>4)*8 + e
__global__ __launch_bounds__(256)
void convert_weights(const float* __restrict__ W1, const float* __restrict__ W2,
                     unsigned short* __restrict__ W1f, unsigned short* __restrict__ W2c) {
    if (blockIdx.x == 128) {
        if (threadIdx.x < H) W2c[threadIdx.x] = f2bf(W2[threadIdx.x]);
        return;
    }
    int idx = blockIdx.x * 256 + threadIdx.x;          // [0, 32768)
    int e     = idx & 7;
    int chunk = idx >> 3;
    int lane  = chunk & 63;
    int ks    = (chunk >> 6) & 3;
    int cf    = (chunk >> 8) & 3;
    int wid   = chunk >> 10;
    int col   = wid * 64 + (lane & 15) + cf * 16;
    int k     = ks * 32 + (lane >> 4) * 8 + e;
    W1f[idx] = f2bf(W1[(size_t)(col & 127) * 256 + (size_t)(col >> 7) * H + k]);
}

__global__ __launch_bounds__(256)
void precompute_P_mfma(const float* __restrict__ emb,
                       const unsigned short* __restrict__ W1f,
                       const float* __restrict__ b1,
                       unsigned short* __restrict__ P,
                       int n_nodes) {
    __shared__ __align__(16) char ldsbuf[BM * CPAD_SH * 2];   // 16896B; A-tile then C-tile (aliased)
    unsigned short* ldsA = (unsigned short*)ldsbuf;           // 8KB swizzled bf16 A
    unsigned short* ldsC = (unsigned short*)ldsbuf;           // 32 x 264 shorts (after barrier)

    int tid  = threadIdx.x;
    int lane = tid & 63;
    int wid  = tid >> 6;
    int block0 = blockIdx.x * BM;
    if (block0 + BM > n_nodes) block0 = n_nodes - BM;   // overlap tail (same values rewritten)
    if (block0 < 0) block0 = 0;

    // B fragments: fully coalesced 1KB/inst from fragment-ready W1f (L2-hot)
    frag_ab Bf[4][4];
#pragma unroll
    for (int cf = 0; cf < 4; ++cf)
#pragma unroll
        for (int ks = 0; ks < 4; ++ks)
            Bf[cf][ks] = *(const frag_ab*)(W1f + ((((size_t)wid * 4 + cf) * 4 + ks) * 64 + lane) * 8);

    // stage A tile: 32 rows x 128 k, fp32 -> bf16, XOR-swizzled LDS
    {
        int row = tid >> 3;                  // 0..31, 8 threads/row
        int q   = tid & 7;                   // 16-k chunk
        int grow = block0 + row;
        const float4* src = (const float4*)(emb + (size_t)grow * H + q * 16);
#pragma unroll
        for (int i = 0; i < 2; ++i) {
            float4 a = src[2 * i], b = src[2 * i + 1];
            ushort8 v;
            v[0] = f2bf(a.x); v[1] = f2bf(a.y); v[2] = f2bf(a.z); v[3] = f2bf(a.w);
            v[4] = f2bf(b.x); v[5] = f2bf(b.y); v[6] = f2bf(b.z); v[7] = f2bf(b.w);
            int k0 = q * 16 + i * 8;
            int byte = (row * 256 + k0 * 2) ^ ((row & 7) << 4);
            *(ushort8*)((char*)ldsA + byte) = v;
        }
    }
    __syncthreads();

    // MFMA: each wave computes [32 rows x 64 cols]
    f32x4 acc[2][4];
#pragma unroll
    for (int mf = 0; mf < 2; ++mf)
#pragma unroll
        for (int cf = 0; cf < 4; ++cf) acc[mf][cf] = (f32x4){0.f, 0.f, 0.f, 0.f};

#pragma unroll
    for (int ks = 0; ks < 4; ++ks) {
        frag_ab Af[2];
#pragma unroll
        for (int mf = 0; mf < 2; ++mf) {
            int row = mf * 16 + (lane & 15);
            int k   = ks * 32 + (lane >> 4) * 8;
            int byte = (row * 256 + k * 2) ^ ((row & 7) << 4);
            Af[mf] = *(const frag_ab*)((const char*)ldsA + byte);
        }
#pragma unroll
        for (int mf = 0; mf < 2; ++mf)
#pragma unroll
            for (int cf = 0; cf < 4; ++cf)
                acc[mf][cf] = __builtin_amdgcn_mfma_f32_16x16x32_bf16(
                    Af[mf], Bf[cf][ks], acc[mf][cf], 0, 0, 0);
    }

    __syncthreads();   // all Af reads done -> safe to overwrite ldsbuf with C-tile

    // epilogue pt1: +b1, cvt, write C-tile to padded LDS
    {
        int colbase = wid * 64 + (lane & 15);
        int rbase   = (lane >> 4) * 4;
        float b1c[4];
#pragma unroll
        for (int cf = 0; cf < 4; ++cf) {
            int col = colbase + cf * 16;
            b1c[cf] = (col < H) ? b1[col] : 0.f;
        }
#pragma unroll
        for (int mf = 0; mf < 2; ++mf)
#pragma unroll
            for (int cf = 0; cf < 4; ++cf) {
                int col = colbase + cf * 16;
#pragma unroll
                for (int r = 0; r < 4; ++r) {
                    int row = mf * 16 + rbase + r;
                    ldsC[row * CPAD_SH + col] = f2bf(acc[mf][cf][r] + b1c[cf]);
                }
            }
    }
    __syncthreads();

    // epilogue pt2: stream C-tile out, fully coalesced 16B/lane (complete lines)
#pragma unroll
    for (int it = 0; it < 4; ++it) {
        int c   = it * 256 + tid;        // 16B chunk id, [0, 1024)
        int row = c >> 5;
        int off = c & 31;
        ushort8 v = *(const ushort8*)((const char*)ldsC + row * (CPAD_SH * 2) + off * 16);
        *(ushort8*)((char*)P + (size_t)(block0 + row) * 512 + off * 16) = v;
    }
}

__global__ __launch_bounds__(256)
void edge_score_mfma(const unsigned short* __restrict__ P,
                     const unsigned short* __restrict__ W2c,
                     const float* __restrict__ b2,
                     const int* __restrict__ src,
                     const int* __restrict__ dst,
                     float* __restrict__ out,
                     int n_edges) {
    int lane = threadIdx.x & 63;
    int wave = blockIdx.x * 4 + (threadIdx.x >> 6);
    int e0 = wave * EPW;
    if (e0 >= n_edges) return;

    frag_ab Bf[4];
    {
        int krun = (lane >> 4) * 8;
#pragma unroll
        for (int ks = 0; ks < 4; ++ks)
            Bf[ks] = *(const frag_ab*)(W2c + ks * 32 + krun);
    }
    float b2v = b2[0];
    int el = lane & 15;
    int kb = (lane >> 4) * 16;

    int eA = e0 + el;       if (eA > n_edges - 1) eA = n_edges - 1;
    int eB = e0 + 16 + el;  if (eB > n_edges - 1) eB = n_edges - 1;
    const char* pb = (const char*)P;
    const char* sA = pb + (size_t)src[eA] * 512 + kb;
    const char* dA = pb + (size_t)dst[eA] * 512 + 256 + kb;
    const char* sB = pb + (size_t)src[eB] * 512 + kb;
    const char* dB = pb + (size_t)dst[eB] * 512 + 256 + kb;

    uint4v rsA[4], rdA[4], rsB[4], rdB[4];
#pragma unroll
    for (int ks = 0; ks < 4; ++ks) {        // 16 independent gathers in flight
        rsA[ks] = *(const uint4v*)(sA + ks * 64);
        rdA[ks] = *(const uint4v*)(dA + ks * 64);
        rsB[ks] = *(const uint4v*)(sB + ks * 64);
        rdB[ks] = *(const uint4v*)(dB + ks * 64);
    }

    f32x4 accA = (f32x4){0.f, 0.f, 0.f, 0.f};
    f32x4 accB = (f32x4){0.f, 0.f, 0.f, 0.f};
#pragma unroll
    for (int ks = 0; ks < 4; ++ks) {
        accA = __builtin_amdgcn_mfma_f32_16x16x32_bf16(relu_sum(rsA[ks], rdA[ks]), Bf[ks], accA, 0, 0, 0);
        accB = __builtin_amdgcn_mfma_f32_16x16x32_bf16(relu_sum(rsB[ks], rdB[ks]), Bf[ks], accB, 0, 0, 0);
    }

    if (el == 0) {
        int r0 = (lane >> 4) * 4;
        int ea = e0 + r0, eb = e0 + 16 + r0;
        float4 oA = { accA[0] + b2v, accA[1] + b2v, accA[2] + b2v, accA[3] + b2v };
        float4 oB = { accB[0] + b2v, accB[1] + b2v, accB[2] + b2v, accB[3] + b2v };
        if (eb + 3 < n_edges) {
            *(float4*)(out + ea) = oA;
            *(float4*)(out + eb) = oB;
        } else {
#pragma unroll
            for (int r = 0; r < 4; ++r) {
                if (ea + r < n_edges) out[ea + r] = accA[r] + b2v;
                if (eb + r < n_edges) out[eb + r] = accB[r] + b2v;
            }
        }
    }
}

// Fallback if workspace too small (correctness-first, slow).
__global__ __launch_bounds__(128)
void naive_edge(const float* __restrict__ emb,
                const float* __restrict__ W1,
                const float* __restrict__ b1,
                const float* __restrict__ W2,
                const float* __restrict__ b2,
                const int* __restrict__ src,
                const int* __restrict__ dst,
                float* __restrict__ out,
                int n_edges) {
    __shared__ float es[H], ed[H];
    __shared__ float red[2];
    int e = blockIdx.x;
    if (e >= n_edges) return;
    int j = threadIdx.x;
    int s = src[e], d = dst[e];
    es[j] = emb[(size_t)s * H + j];
    ed[j] = emb[(size_t)d * H + j];
    __syncthreads();
    const float* w = W1 + (size_t)j * 256;
    float acc = b1[j];
    for (int k = 0; k < H; ++k) acc += es[k] * w[k] + ed[k] * w[H + k];
    acc = acc > 0.f ? acc : 0.f;
    float p = acc * W2[j];
#pragma unroll
    for (int off = 32; off; off >>= 1) p += __shfl_xor(p, off, 64);
    int lane = j & 63, wid = j >> 6;
    if (lane == 0) red[wid] = p;
    __syncthreads();
    if (j == 0) out[e] = red[0] + red[1] + b2[0];
}

extern "C" void kernel_launch(void* const* d_in, const int* in_sizes, int n_in,
                              void* d_out, int out_size, void* d_ws, size_t ws_size,
                              hipStream_t stream) {
    const float* emb = (const float*)d_in[0];   // [N, 128]
    const float* W1  = (const float*)d_in[1];   // [128, 256]
    const float* b1  = (const float*)d_in[2];   // [128]
    const float* W2  = (const float*)d_in[3];   // [1, 128]
    const float* b2  = (const float*)d_in[4];   // [1]
    const int*   src = (const int*)d_in[5];     // [E]
    const int*   dst = (const int*)d_in[6];     // [E]
    float* out = (float*)d_out;

    int n_nodes = in_sizes[0] / H;
    int n_edges = in_sizes[5];

    size_t needP = (size_t)n_nodes * NJJ * sizeof(unsigned short);
    size_t offW1 = (needP + 255) & ~(size_t)255;
    size_t offW2 = offW1 + (size_t)NJJ * H * sizeof(unsigned short);
    size_t need  = offW2 + 256;

    if (ws_size >= need && n_nodes >= BM) {
        unsigned short* P   = (unsigned short*)d_ws;
        unsigned short* W1f = (unsigned short*)((char*)d_ws + offW1);
        unsigned short* W2c = (unsigned short*)((char*)d_ws + offW2);
        convert_weights<<<129, 256, 0, stream>>>(W1, W2, W1f, W2c);
        int grid1 = (n_nodes + BM - 1) / BM;
        precompute_P_mfma<<<grid1, 256, 0, stream>>>(emb, W1f, b1, P, n_nodes);
        int grid2 = (n_edges + EPW * 4 - 1) / (EPW * 4);
        edge_score_mfma<<<grid2, 256, 0, stream>>>(P, W2c, b2, src, dst, out, n_edges);
    } else {
        naive_edge<<<n_edges, 128, 0, stream>>>(emb, W1, b1, W2, b2, src, dst, out, n_edges);
    }
}